// Round 3
// baseline (3941.593 us; speedup 1.0000x reference)
//
#include <hip/hip_runtime.h>
#include <math.h>

#define TSTEPS 512
#define B      64
#define I      512
#define H      512
#define G      2048   // 4*H
#define K      1024   // I + H
#define NBLK   64     // persistent-kernel grid

typedef __attribute__((ext_vector_type(8))) short          short8;  // MFMA frag
typedef __attribute__((ext_vector_type(8))) unsigned short u16x8;
typedef __attribute__((ext_vector_type(4))) float          f32x4;

__device__ __forceinline__ unsigned short f2bf(float f) {
    union { float f; unsigned int u; } v; v.f = f;
    unsigned int r = v.u + 0x7fffu + ((v.u >> 16) & 1u);   // RNE
    return (unsigned short)(r >> 16);
}
__device__ __forceinline__ float bf2f(unsigned short b) {
    union { unsigned int u; float f; } v; v.u = ((unsigned int)b) << 16;
    return v.f;
}

// packed-col mapping (both paths): col = nb*32 + gate*8 + hj
//                               <-> g = gate*H + nb*8 + hj   (nb = col>>5)
__device__ __forceinline__ int col2g(int col) {
    int w = col & 31, nb = col >> 5;
    return (w >> 3) * H + nb * 8 + (w & 7);
}

// ===========================================================================
// Shared init: hb0 (bf16 of hx), cbuf (fp32 cx), packed bias2
// ===========================================================================
__global__ void init_state(const float* __restrict__ hx,
                           const float* __restrict__ cx,
                           const float* __restrict__ bih,
                           const float* __restrict__ bhh,
                           unsigned short* __restrict__ hbf0,
                           float* __restrict__ cbuf,
                           float* __restrict__ bias2) {
    int i = blockIdx.x * 256 + threadIdx.x;
    if (i < B * H) { hbf0[i] = f2bf(hx[i]); cbuf[i] = cx[i]; }
    if (i < G) bias2[i] = bih[col2g(i)] + bhh[col2g(i)];
}

// ===========================================================================
// PERSISTENT PATH
// ===========================================================================

// input fp32 -> bf16, flat
__global__ void conv_x(const float* __restrict__ in, unsigned short* __restrict__ xbf) {
    int i = blockIdx.x * 256 + threadIdx.x;     // 8 elems per thread
    size_t base = (size_t)i * 8;
    float4 a = *(const float4*)(in + base);
    float4 b = *(const float4*)(in + base + 4);
    u16x8 o;
    o[0]=f2bf(a.x); o[1]=f2bf(a.y); o[2]=f2bf(a.z); o[3]=f2bf(a.w);
    o[4]=f2bf(b.x); o[5]=f2bf(b.y); o[6]=f2bf(b.z); o[7]=f2bf(b.w);
    *(u16x8*)(xbf + base) = o;
}

// wih, whh -> packed bf16 [col][k] (K=512 each)
__global__ void pack_w2(const float* __restrict__ wih,
                        const float* __restrict__ whh,
                        unsigned short* __restrict__ wihP,
                        unsigned short* __restrict__ whhP) {
    int idx = blockIdx.x * 256 + threadIdx.x;   // [0, G*128)
    int col = idx >> 7;
    int k0  = (idx & 127) << 2;
    int g = col2g(col);
    float4 a = *(const float4*)(wih + (size_t)g * I + k0);
    float4 b = *(const float4*)(whh + (size_t)g * H + k0);
    ushort4 oa = { f2bf(a.x), f2bf(a.y), f2bf(a.z), f2bf(a.w) };
    ushort4 ob = { f2bf(b.x), f2bf(b.y), f2bf(b.z), f2bf(b.w) };
    *(ushort4*)(wihP + (size_t)col * I + k0) = oa;
    *(ushort4*)(whhP + (size_t)col * H + k0) = ob;
}

// xp[nb][t][b][32] = (xbf[t*64+b] . wihP[col]) bf16.  grid (512 t, 16 ncb), 256 thr.
#define LDA 136
#define LDB 136
__global__ __launch_bounds__(256) void xproj_gemm(
    const unsigned short* __restrict__ xbf,   // [T*B][I]
    const unsigned short* __restrict__ wihP,  // [G][I]
    unsigned short* __restrict__ xp)          // [64][512][64][32]
{
    __shared__ unsigned short atile[64 * LDA];    // 17.4 KB
    __shared__ unsigned short btile[128 * LDB];   // 34.8 KB

    const int t   = blockIdx.x;
    const int ncb = blockIdx.y;
    const int tid  = threadIdx.x;
    const int lane = tid & 63;
    const int wv   = tid >> 6;          // 4 waves: mt=wv&1 (32 rows), nt=wv>>1 (64 cols)
    const int fr   = lane & 15;
    const int fk   = (lane >> 4) * 8;
    const int mt   = wv & 1;
    const int nt   = wv >> 1;

    f32x4 acc[2][4];
    #pragma unroll
    for (int mi = 0; mi < 2; ++mi)
        #pragma unroll
        for (int ni = 0; ni < 4; ++ni) acc[mi][ni] = (f32x4){0.f,0.f,0.f,0.f};

    const int arow = tid >> 2, aseg = tid & 3;      // A: 64 rows, 4 thr/row
    const int brow = tid >> 1, bseg = tid & 1;      // B: 128 rows, 2 thr/row

    for (int kt = 0; kt < I; kt += 128) {
        {
            const u16x8* src = (const u16x8*)(xbf + ((size_t)t * 64 + arow) * I + kt);
            #pragma unroll
            for (int j = 0; j < 4; ++j) {
                int ch = aseg + 4 * j;
                *(u16x8*)(atile + arow * LDA + ch * 8) = src[ch];
            }
        }
        {
            const u16x8* src = (const u16x8*)(wihP + ((size_t)ncb * 128 + brow) * I + kt);
            #pragma unroll
            for (int j = 0; j < 8; ++j) {
                int ch = bseg + 2 * j;
                *(u16x8*)(btile + brow * LDB + ch * 8) = src[ch];
            }
        }
        __syncthreads();
        #pragma unroll
        for (int ks = 0; ks < 4; ++ks) {
            short8 af[2], bf[4];
            #pragma unroll
            for (int mi = 0; mi < 2; ++mi)
                af[mi] = *(const short8*)(atile + (mt*32 + mi*16 + fr) * LDA + fk + ks*32);
            #pragma unroll
            for (int ni = 0; ni < 4; ++ni)
                bf[ni] = *(const short8*)(btile + (nt*64 + ni*16 + fr) * LDB + fk + ks*32);
            #pragma unroll
            for (int mi = 0; mi < 2; ++mi)
                #pragma unroll
                for (int ni = 0; ni < 4; ++ni)
                    acc[mi][ni] = __builtin_amdgcn_mfma_f32_16x16x32_bf16(af[mi], bf[ni], acc[mi][ni], 0, 0, 0);
        }
        __syncthreads();
    }

    #pragma unroll
    for (int mi = 0; mi < 2; ++mi)
        #pragma unroll
        for (int ni = 0; ni < 4; ++ni)
            #pragma unroll
            for (int e = 0; e < 4; ++e) {
                int row = mt*32 + mi*16 + (lane >> 4) * 4 + e;       // = b
                int c   = ncb*128 + nt*64 + ni*16 + fr;              // packed col
                int nbv = c >> 5, coff = c & 31;
                xp[(((size_t)nbv * TSTEPS + t) * 64 + row) * 32 + coff] = f2bf(acc[mi][ni][e]);
            }
}

// grid-wide barrier: cumulative counter, device scope
__device__ __forceinline__ void gsync(unsigned int* bar, unsigned int target) {
    __syncthreads();
    if (threadIdx.x == 0) {
        __threadfence();   // release: write-back
        __hip_atomic_fetch_add(bar, 1u, __ATOMIC_RELEASE, __HIP_MEMORY_SCOPE_AGENT);
        while (__hip_atomic_load(bar, __ATOMIC_RELAXED, __HIP_MEMORY_SCOPE_AGENT) < target)
            __builtin_amdgcn_s_sleep(1);
        __threadfence();   // acquire: invalidate
    }
    __syncthreads();
}

// Persistent LSTM: 64 blocks x 512 thr. Block nb owns packed cols nb*32..+32
// (all 4 gates of h-indices nb*8..+8) for all 64 batch rows. whh slice in LDS
// once; c in registers; h via global bf16 ping-pong + grid barrier per step.
#define LDH 520
#define LDW 520
__global__ __launch_bounds__(512) void lstm_persist(
    const unsigned short* __restrict__ xp,     // [64][512][64][32]
    const unsigned short* __restrict__ whhP,   // [G][H]
    const float* __restrict__ bias2,           // [G] packed
    const float* __restrict__ cx,              // [B][H]
    unsigned short* __restrict__ hb0,          // [B][H] (holds h init)
    unsigned short* __restrict__ hb1,
    float* __restrict__ out,                   // [2][B][H]
    unsigned int* __restrict__ bar)
{
    __shared__ unsigned short hsm[64 * LDH];   // 66.6 KB
    __shared__ unsigned short wsm[32 * LDW];   // 33.3 KB
    __shared__ float gbuf[64][33];             //  8.4 KB

    const int tid  = threadIdx.x;
    const int nb   = blockIdx.x;               // [0,64)
    const int lane = tid & 63;
    const int wv   = tid >> 6;                 // [0,8)
    const int fr   = lane & 15;
    const int fk   = (lane >> 4) * 8;
    const int mt   = wv & 3;                   // 4 m-tiles of 16 rows
    const int nt   = wv >> 2;                  // 2 n-tiles of 16 cols

    // stage whh slice once: 32 cols x 512 k
    {
        int row = tid >> 4, seg = tid & 15;
        const u16x8* src = (const u16x8*)(whhP + ((size_t)nb * 32 + row) * H);
        #pragma unroll
        for (int j = 0; j < 4; ++j) {
            int ch = seg + 16 * j;
            *(u16x8*)(wsm + row * LDW + ch * 8) = src[ch];
        }
    }

    const int b  = tid >> 3;                   // [0,64)
    const int hj = tid & 7;                    // [0,8)
    const int hcol = nb * 8 + hj;
    float creg = cx[(size_t)b * H + hcol];
    const float bi = bias2[nb*32 +  0 + hj];
    const float bfv= bias2[nb*32 +  8 + hj];
    const float bg = bias2[nb*32 + 16 + hj];
    const float bo = bias2[nb*32 + 24 + hj];

    const int srow = tid >> 3, sseg = tid & 7; // h staging: 8 thr/row
    float hout = 0.f;

    for (int t = 0; t < TSTEPS; ++t) {
        const unsigned short* hp = (t & 1) ? hb1 : hb0;
        unsigned short*       hn = (t & 1) ? hb0 : hb1;

        // prefetch this thread's 4 gate pre-activations (contiguous 4KB/block)
        const unsigned short* xpt = xp + (((size_t)nb * TSTEPS + t) * 64 + b) * 32;
        unsigned short xi = xpt[ 0 + hj];
        unsigned short xf = xpt[ 8 + hj];
        unsigned short xg = xpt[16 + hj];
        unsigned short xo = xpt[24 + hj];

        // stage h_prev -> LDS (padded rows)
        {
            const u16x8* src = (const u16x8*)(hp + (size_t)srow * H);
            #pragma unroll
            for (int j = 0; j < 8; ++j) {
                int ch = sseg + 8 * j;
                *(u16x8*)(hsm + srow * LDH + ch * 8) = src[ch];
            }
        }
        __syncthreads();

        // gates[64 x 32] = h[64 x 512] . whh_slice[512 x 32]
        f32x4 accA = {0.f,0.f,0.f,0.f}, accB = {0.f,0.f,0.f,0.f};
        const unsigned short* ap = hsm + (mt*16 + fr) * LDH + fk;
        const unsigned short* bp = wsm + (nt*16 + fr) * LDW + fk;
        #pragma unroll
        for (int ks = 0; ks < 16; ++ks) {
            short8 af = *(const short8*)(ap + ks * 32);
            short8 bf = *(const short8*)(bp + ks * 32);
            if (ks & 1) accB = __builtin_amdgcn_mfma_f32_16x16x32_bf16(af, bf, accB, 0, 0, 0);
            else        accA = __builtin_amdgcn_mfma_f32_16x16x32_bf16(af, bf, accA, 0, 0, 0);
        }
        #pragma unroll
        for (int e = 0; e < 4; ++e)
            gbuf[mt*16 + (lane >> 4)*4 + e][nt*16 + fr] = accA[e] + accB[e];
        __syncthreads();

        // cell update (c in registers)
        {
            float ig = gbuf[b][ 0 + hj] + bf2f(xi) + bi;
            float fg = gbuf[b][ 8 + hj] + bf2f(xf) + bfv;
            float gg = gbuf[b][16 + hj] + bf2f(xg) + bg;
            float og = gbuf[b][24 + hj] + bf2f(xo) + bo;
            ig = 1.f / (1.f + __expf(-ig));
            fg = 1.f / (1.f + __expf(-fg));
            og = 1.f / (1.f + __expf(-og));
            gg = tanhf(gg);
            creg = fg * creg + ig * gg;
            hout = og * tanhf(creg);
            if (t < TSTEPS - 1) hn[(size_t)b * H + hcol] = f2bf(hout);
        }

        if (t < TSTEPS - 1) gsync(bar, (unsigned)(t + 1) * NBLK);
    }

    out[(size_t)b * H + hcol] = hout;                 // hy (fp32, from regs)
    out[(size_t)B * H + (size_t)b * H + hcol] = creg; // cy
}

// ===========================================================================
// FALLBACK PATH (round-2, proven): per-step launches, K=1024
// ===========================================================================
#define KT  256
#define LDP 264

__global__ void pack_w(const float* __restrict__ wih,
                       const float* __restrict__ whh,
                       unsigned short* __restrict__ wbf) {
    int idx = blockIdx.x * 256 + threadIdx.x;
    int col = idx >> 8;
    int k0  = (idx & 255) << 2;
    int g = col2g(col);
    float4 v = (k0 < I) ? *(const float4*)(wih + (size_t)g * I + k0)
                        : *(const float4*)(whh + (size_t)g * H + (k0 - I));
    ushort4 o = { f2bf(v.x), f2bf(v.y), f2bf(v.z), f2bf(v.w) };
    *(ushort4*)(wbf + (size_t)col * K + k0) = o;
}

__global__ __launch_bounds__(256) void lstm_step(
    const float* __restrict__ x_t,
    const unsigned short* __restrict__ wbf,
    const float* __restrict__ bias2,
    const unsigned short* __restrict__ h_prev,
    unsigned short* __restrict__ h_next,
    float* __restrict__ c)
{
    __shared__ unsigned short xs [32 * LDP];
    __shared__ unsigned short wsm2[32 * LDP];
    __shared__ float gbuf[32][33];

    const int tid  = threadIdx.x;
    const int mg   = blockIdx.x;
    const int nb   = blockIdx.y;
    const int lane = tid & 63;
    const int wv   = tid >> 6;
    const int rbase = mg * 32;
    const int cbase = nb * 32;
    const int fr = lane & 15;
    const int fk = (lane >> 4) * 8;
    const int sr = tid >> 3;
    const int sc = (tid & 7) * 8;

    f32x4 accA = {0.f,0.f,0.f,0.f}, accB = {0.f,0.f,0.f,0.f};

    for (int kt = 0; kt < K; kt += KT) {
        if (kt < I) {
            const float* src = x_t + (size_t)(rbase + sr) * I + kt;
            unsigned short* dst = xs + sr * LDP;
            #pragma unroll
            for (int j = 0; j < 4; ++j) {
                int k = sc + j * 64;
                float4 a = *(const float4*)(src + k);
                float4 b = *(const float4*)(src + k + 4);
                u16x8 o;
                o[0]=f2bf(a.x); o[1]=f2bf(a.y); o[2]=f2bf(a.z); o[3]=f2bf(a.w);
                o[4]=f2bf(b.x); o[5]=f2bf(b.y); o[6]=f2bf(b.z); o[7]=f2bf(b.w);
                *(u16x8*)(dst + k) = o;
            }
        } else {
            const unsigned short* src = h_prev + (size_t)(rbase + sr) * H + (kt - I);
            unsigned short* dst = xs + sr * LDP;
            #pragma unroll
            for (int j = 0; j < 4; ++j) {
                int k = sc + j * 64;
                *(u16x8*)(dst + k) = *(const u16x8*)(src + k);
            }
        }
        {
            const unsigned short* src = wbf + (size_t)(cbase + sr) * K + kt;
            unsigned short* dst = wsm2 + sr * LDP;
            #pragma unroll
            for (int j = 0; j < 4; ++j) {
                int k = sc + j * 64;
                *(u16x8*)(dst + k) = *(const u16x8*)(src + k);
            }
        }
        __syncthreads();
        const unsigned short* ap = xs   + ((wv & 1) * 16 + fr) * LDP + fk;
        const unsigned short* bp = wsm2 + ((wv >> 1) * 16 + fr) * LDP + fk;
        #pragma unroll
        for (int ks = 0; ks < KT / 32; ++ks) {
            short8 af = *(const short8*)(ap + ks * 32);
            short8 bf = *(const short8*)(bp + ks * 32);
            if (ks & 1) accB = __builtin_amdgcn_mfma_f32_16x16x32_bf16(af, bf, accB, 0, 0, 0);
            else        accA = __builtin_amdgcn_mfma_f32_16x16x32_bf16(af, bf, accA, 0, 0, 0);
        }
        __syncthreads();
    }

    #pragma unroll
    for (int e = 0; e < 4; ++e)
        gbuf[(wv & 1) * 16 + (lane >> 4) * 4 + e][(wv >> 1) * 16 + fr] = accA[e] + accB[e];
    __syncthreads();

    {
        int br = tid >> 3;
        int hj = tid & 7;
        float ig = gbuf[br][ 0 + hj] + bias2[cbase +  0 + hj];
        float fg = gbuf[br][ 8 + hj] + bias2[cbase +  8 + hj];
        float gg = gbuf[br][16 + hj] + bias2[cbase + 16 + hj];
        float og = gbuf[br][24 + hj] + bias2[cbase + 24 + hj];
        ig = 1.f / (1.f + __expf(-ig));
        fg = 1.f / (1.f + __expf(-fg));
        og = 1.f / (1.f + __expf(-og));
        gg = tanhf(gg);
        size_t ci = (size_t)(rbase + br) * H + nb * 8 + hj;
        float cn = fg * c[ci] + ig * gg;
        c[ci] = cn;
        h_next[ci] = f2bf(og * tanhf(cn));
    }
}

__global__ void epilogue(const unsigned short* __restrict__ hbf,
                         const float* __restrict__ cfin,
                         float* __restrict__ out) {
    int i = blockIdx.x * 256 + threadIdx.x;
    if (i < B * H) {
        out[i] = bf2f(hbf[i]);
        out[B * H + i] = cfin[i];
    }
}

// ===========================================================================
extern "C" void kernel_launch(void* const* d_in, const int* in_sizes, int n_in,
                              void* d_out, int out_size, void* d_ws, size_t ws_size,
                              hipStream_t stream) {
    const float* input = (const float*)d_in[0];
    const float* hx    = (const float*)d_in[1];
    const float* cx    = (const float*)d_in[2];
    const float* wih   = (const float*)d_in[3];
    const float* whh   = (const float*)d_in[4];
    const float* bih   = (const float*)d_in[5];
    const float* bhh   = (const float*)d_in[6];
    float* out = (float*)d_out;
    char* ws = (char*)d_ws;

    const size_t PERSIST_WS = 172236864ULL;

    if (ws_size >= PERSIST_WS) {
        // ---- persistent path ----
        unsigned short* xpBuf = (unsigned short*)(ws);                 // 128 MB
        unsigned short* xbf   = (unsigned short*)(ws + 134217728);     // 32 MB
        unsigned short* wihP  = (unsigned short*)(ws + 167772160);     // 2 MB
        unsigned short* whhP  = (unsigned short*)(ws + 169869312);     // 2 MB
        float*          bias2 = (float*)         (ws + 171966464);     // 8 KB
        unsigned short* hb0   = (unsigned short*)(ws + 171974656);     // 64 KB
        unsigned short* hb1   = (unsigned short*)(ws + 172040192);     // 64 KB
        float*          cbuf  = (float*)         (ws + 172105728);     // 128 KB (init compat)
        unsigned int*   bar   = (unsigned int*)  (ws + 172236800);

        hipMemsetAsync(bar, 0, 64, stream);
        conv_x<<<(TSTEPS * B * I) / (256 * 8), 256, 0, stream>>>(input, xbf);
        pack_w2<<<(G * 128) / 256, 256, 0, stream>>>(wih, whh, wihP, whhP);
        init_state<<<B * H / 256, 256, 0, stream>>>(hx, cx, bih, bhh, hb0, cbuf, bias2);
        dim3 ggrid(TSTEPS, G / 128);
        xproj_gemm<<<ggrid, 256, 0, stream>>>(xbf, wihP, xpBuf);
        lstm_persist<<<NBLK, 512, 0, stream>>>(xpBuf, whhP, bias2, cx, hb0, hb1, out, bar);
    } else {
        // ---- fallback: round-2 per-step launches ----
        unsigned short* wbf   = (unsigned short*)(ws);
        float*          bias2 = (float*)(ws + 4194304);
        float*          cbuf  = (float*)(ws + 4194304 + 8192);
        unsigned short* hbf0  = (unsigned short*)(ws + 4333568);
        unsigned short* hbf1  = (unsigned short*)(ws + 4399104);

        pack_w<<<G * K / 4 / 256, 256, 0, stream>>>(wih, whh, wbf);
        init_state<<<B * H / 256, 256, 0, stream>>>(hx, cx, bih, bhh, hbf0, cbuf, bias2);
        dim3 grid(2, 64);
        for (int t = 0; t < TSTEPS; ++t) {
            lstm_step<<<grid, 256, 0, stream>>>(
                input + (size_t)t * B * I, wbf, bias2,
                (t & 1) ? hbf1 : hbf0,
                (t & 1) ? hbf0 : hbf1,
                cbuf);
        }
        epilogue<<<B * H / 256, 256, 0, stream>>>(hbf0, cbuf, out);
    }
}